// Round 6
// baseline (439.649 us; speedup 1.0000x reference)
//
#include <hip/hip_runtime.h>
#include <hip/hip_fp16.h>

#define FDIM 64
#define EPS 1e-5f
#define NBUCK 1024     // coarse buckets = high bits of 17-bit id
#define LOWB 7
#define LOWMASK 127
#define RB 256         // radix blocks
#define RT 1024        // radix threads per block
#define GRP 16         // rows per scan group (RB/GRP groups)
#define NSLOT 8        // accumulator slots to spread atomic RMW lines

typedef float v2f __attribute__((ext_vector_type(2)));

// ---------------- per-block coarse histograms of src>>7 and dst>>7 ----------------
__global__ void k_hist(const int* __restrict__ src, const int* __restrict__ dst,
                       int* __restrict__ histS, int* __restrict__ histD, int E, int chunk) {
    __shared__ int hs[NBUCK], hd[NBUCK];
    int tid = threadIdx.x;            // RT == NBUCK == 1024
    hs[tid] = 0; hd[tid] = 0;
    __syncthreads();
    int b = blockIdx.x;
    int beg = b * chunk;
    int end = min(E, beg + chunk);
    int i = beg + tid * 4;
    for (; i + 3 < end; i += RT * 4) {
        int4 s = *(const int4*)(src + i);
        int4 d = *(const int4*)(dst + i);
        atomicAdd(&hs[s.x >> LOWB], 1); atomicAdd(&hd[d.x >> LOWB], 1);
        atomicAdd(&hs[s.y >> LOWB], 1); atomicAdd(&hd[d.y >> LOWB], 1);
        atomicAdd(&hs[s.z >> LOWB], 1); atomicAdd(&hd[d.z >> LOWB], 1);
        atomicAdd(&hs[s.w >> LOWB], 1); atomicAdd(&hd[d.w >> LOWB], 1);
    }
    if (i < end) {
        for (int j = i; j < end && j < i + 4; ++j) {
            atomicAdd(&hs[src[j] >> LOWB], 1);
            atomicAdd(&hd[dst[j] >> LOWB], 1);
        }
    }
    __syncthreads();
    histS[b * NBUCK + tid] = hs[tid];
    histD[b * NBUCK + tid] = hd[tid];
}

// ---------------- scan A: per-group column partial sums (fully parallel) ----------------
__global__ void k_scanA(const int* __restrict__ histS, const int* __restrict__ histD,
                        int* __restrict__ psumS, int* __restrict__ psumD) {
    int bid = blockIdx.x;
    int m = bid >> 6;                 // 0 = S, 1 = D
    int g = (bid >> 2) & (RB / GRP - 1);
    int c = bid & 3;
    const int* hist = m ? histD : histS;
    int* psum = m ? psumD : psumS;
    int k = c * 256 + threadIdx.x;
    int s = 0;
#pragma unroll
    for (int r = 0; r < GRP; ++r)
        s += hist[(g * GRP + r) * NBUCK + k];
    psum[g * NBUCK + k] = s;
}

// ---------------- scan B: group-level scan + bucket-base scan ----------------
__global__ void k_scanB(const int* __restrict__ psumS, int* __restrict__ baseS,
                        int* __restrict__ grpbaseS,
                        const int* __restrict__ psumD, int* __restrict__ baseD,
                        int* __restrict__ grpbaseD) {
    const int* psum = blockIdx.x ? psumD : psumS;
    int* base    = blockIdx.x ? baseD : baseS;
    int* grpbase = blockIdx.x ? grpbaseD : grpbaseS;
    __shared__ int s[NBUCK];
    int k = threadIdx.x;
    int ge[RB / GRP];
    int run = 0;
#pragma unroll
    for (int g = 0; g < RB / GRP; ++g) { ge[g] = run; run += psum[g * NBUCK + k]; }
    s[k] = run;
    __syncthreads();
    for (int off = 1; off < NBUCK; off <<= 1) {
        int t = (k >= off) ? s[k - off] : 0;
        __syncthreads();
        s[k] += t;
        __syncthreads();
    }
    int excl = (k > 0) ? s[k - 1] : 0;
    base[k] = excl;
    if (k == NBUCK - 1) base[NBUCK] = s[NBUCK - 1];
#pragma unroll
    for (int g = 0; g < RB / GRP; ++g)
        grpbase[g * NBUCK + k] = excl + ge[g];
}

// ---------------- coarse partition: LDS cursors per block, no global atomics ----------------
__global__ void k_bucket(const int* __restrict__ src, const int* __restrict__ dst,
                         const int* __restrict__ histS, const int* __restrict__ histD,
                         const int* __restrict__ grpbaseS, const int* __restrict__ grpbaseD,
                         unsigned char* __restrict__ tmpS, int* __restrict__ tmpD,
                         int E, int chunk) {
    __shared__ int curS[NBUCK], curD[NBUCK];
    int tid = threadIdx.x;
    int b = blockIdx.x;
    int g = b / GRP;
    int rs = 0, rd = 0;
    for (int r = g * GRP; r < b; ++r) {
        rs += histS[r * NBUCK + tid];
        rd += histD[r * NBUCK + tid];
    }
    curS[tid] = grpbaseS[g * NBUCK + tid] + rs;
    curD[tid] = grpbaseD[g * NBUCK + tid] + rd;
    __syncthreads();
    int beg = b * chunk;
    int end = min(E, beg + chunk);
    int i = beg + tid * 4;
    for (; i + 3 < end; i += RT * 4) {
        int4 s = *(const int4*)(src + i);
        int4 d = *(const int4*)(dst + i);
        int p;
        p = atomicAdd(&curS[s.x >> LOWB], 1); tmpS[p] = (unsigned char)(s.x & LOWMASK);
        p = atomicAdd(&curS[s.y >> LOWB], 1); tmpS[p] = (unsigned char)(s.y & LOWMASK);
        p = atomicAdd(&curS[s.z >> LOWB], 1); tmpS[p] = (unsigned char)(s.z & LOWMASK);
        p = atomicAdd(&curS[s.w >> LOWB], 1); tmpS[p] = (unsigned char)(s.w & LOWMASK);
        p = atomicAdd(&curD[d.x >> LOWB], 1); tmpD[p] = (s.x << LOWB) | (d.x & LOWMASK);
        p = atomicAdd(&curD[d.y >> LOWB], 1); tmpD[p] = (s.y << LOWB) | (d.y & LOWMASK);
        p = atomicAdd(&curD[d.z >> LOWB], 1); tmpD[p] = (s.z << LOWB) | (d.z & LOWMASK);
        p = atomicAdd(&curD[d.w >> LOWB], 1); tmpD[p] = (s.w << LOWB) | (d.w & LOWMASK);
    }
    if (i < end) {
        for (int j = i; j < end && j < i + 4; ++j) {
            int sv = src[j], dv = dst[j];
            int p = atomicAdd(&curS[sv >> LOWB], 1);
            tmpS[p] = (unsigned char)(sv & LOWMASK);
            p = atomicAdd(&curD[dv >> LOWB], 1);
            tmpD[p] = (sv << LOWB) | (dv & LOWMASK);
        }
    }
}

// ---------------- merged fine pass (one dispatch, two jobs running concurrently) ------
__global__ void k_fine(const int* __restrict__ tmpD, const int* __restrict__ baseD,
                       int* __restrict__ csr_src, int* __restrict__ rowptr,
                       const unsigned char* __restrict__ tmpS, const int* __restrict__ baseS,
                       int* __restrict__ degO, const float* __restrict__ x,
                       unsigned char* __restrict__ buf8, int N, int nbuck) {
    __shared__ int hist[128];
    __shared__ int scanv[128];
    int tid = threadIdx.x;
    if (blockIdx.x < nbuck) {
        int b = blockIdx.x;
        int s0 = baseD[b];
        int s1 = baseD[b + 1];
        if (tid < 128) hist[tid] = 0;
        __syncthreads();
        for (int i = s0 + tid; i < s1; i += 256)
            atomicAdd(&hist[tmpD[i] & LOWMASK], 1);
        __syncthreads();
        int mine = (tid < 128) ? hist[tid] : 0;
        if (tid < 128) scanv[tid] = mine;
        __syncthreads();
        for (int off = 1; off < 128; off <<= 1) {
            int t = (tid < 128 && tid >= off) ? scanv[tid - off] : 0;
            __syncthreads();
            if (tid < 128) scanv[tid] += t;
            __syncthreads();
        }
        if (tid < 128) {
            int excl = scanv[tid] - mine;       // exclusive scan
            int d = (b << LOWB) + tid;
            if (d <= N) rowptr[d] = s0 + excl;  // covers rowptr[N]=E too
            hist[tid] = excl;                   // LDS cursors
        }
        __syncthreads();
        for (int i = s0 + tid; i < s1; i += 256) {
            int p = tmpD[i];
            int pos = atomicAdd(&hist[p & LOWMASK], 1);
            csr_src[s0 + pos] = p >> LOWB;
        }
    } else {
        int b = blockIdx.x - nbuck;
        int s0 = baseS[b];
        int s1 = baseS[b + 1];
        if (tid < 128) hist[tid] = 0;
        __syncthreads();
        for (int i = s0 + tid; i < s1; i += 256)
            atomicAdd(&hist[tmpS[i]], 1);
        __syncthreads();
        if (tid < 128) {
            int d = (b << LOWB) + tid;
            if (d < N) degO[d] = hist[tid];
        }
        // scale x rows, quantize to fp8: thread = (node, half-row part of 32 feats)
        int node = (b << LOWB) + (tid >> 1);
        if (node < N) {
            float rs = rsqrtf((float)max(hist[tid >> 1], 1));
            int part = tid & 1;                 // feats [part*32, part*32+32)
            const float4* xr = (const float4*)(x + (size_t)node * FDIM) + part * 8;
            int4* orow = (int4*)(buf8 + (size_t)node * FDIM + part * 32); // 2 int4 = 32 fp8
            int wbuf[8];
#pragma unroll
            for (int q = 0; q < 4; ++q) {
                float4 a = xr[2 * q];
                float4 c = xr[2 * q + 1];
                int t = __builtin_amdgcn_cvt_pk_fp8_f32(a.x * rs, a.y * rs, 0, false);
                t     = __builtin_amdgcn_cvt_pk_fp8_f32(a.z * rs, a.w * rs, t, true);
                wbuf[2 * q] = t;
                t = __builtin_amdgcn_cvt_pk_fp8_f32(c.x * rs, c.y * rs, 0, false);
                t = __builtin_amdgcn_cvt_pk_fp8_f32(c.z * rs, c.w * rs, t, true);
                wbuf[2 * q + 1] = t;
            }
            orow[0] = make_int4(wbuf[0], wbuf[1], wbuf[2], wbuf[3]);
            orow[1] = make_int4(wbuf[4], wbuf[5], wbuf[6], wbuf[7]);
        }
    }
}

// ---------------- CSR SpMM: 8 rows/wave, 16B/lane gather = 4 requests/edge ------------
__global__ void k_spmm8(const unsigned char* __restrict__ hin, const int* __restrict__ rowptr,
                        const int* __restrict__ csr_src, __half* __restrict__ out, int N) {
    int wid = (blockIdx.x * blockDim.x + threadIdx.x) >> 6;
    int lane = threadIdx.x & 63;
    int g  = lane >> 3;          // output row within wave (8 rows)
    int sl = lane & 7;           // idx slot (8 idx per row, layout unchanged)
    int e  = (lane >> 2) & 1;    // edge parity
    int s  = lane & 3;           // 16B slice of the 64B row
    int row = wid * 8 + g;
    bool rv = row < N;
    int start = rv ? rowptr[row] : 0;
    int end   = rv ? rowptr[row + 1] : 0;
    int deg = end - start;
    int md = deg;
    md = max(md, __shfl_xor(md, 8));
    md = max(md, __shfl_xor(md, 16));
    md = max(md, __shfl_xor(md, 32));
    float acc[16];
#pragma unroll
    for (int q = 0; q < 16; ++q) acc[q] = 0.f;
    int safe = (deg > 0) ? end - 1 : 0;
    int a0 = start + sl;
    int idx_cur = csr_src[(a0 < end) ? a0 : safe];   // in flight across setup
    for (int it = 0; it < md; it += 8) {
        int idx_nxt = 0;
        if (it + 8 < md) {
            int a = start + it + 8 + sl;
            idx_nxt = csr_src[(a < end) ? a : safe]; // prefetch next block's indices
        }
        int b0 = __shfl(idx_cur, (g << 3) + e);
        int b1 = __shfl(idx_cur, (g << 3) + e + 2);
        int b2 = __shfl(idx_cur, (g << 3) + e + 4);
        int b3 = __shfl(idx_cur, (g << 3) + e + 6);
        uint4 r0 = ((const uint4*)(hin + ((size_t)b0 << 6)))[s];
        uint4 r1 = ((const uint4*)(hin + ((size_t)b1 << 6)))[s];
        uint4 r2 = ((const uint4*)(hin + ((size_t)b2 << 6)))[s];
        uint4 r3 = ((const uint4*)(hin + ((size_t)b3 << 6)))[s];
        __builtin_amdgcn_sched_barrier(0);   // pin: all 4 gathers issue before use
        float w0 = (it + e     < deg) ? 1.f : 0.f;
        float w1 = (it + e + 2 < deg) ? 1.f : 0.f;
        float w2 = (it + e + 4 < deg) ? 1.f : 0.f;
        float w3 = (it + e + 6 < deg) ? 1.f : 0.f;
#define ACC16(RV, W) do { \
        v2f t0 = __builtin_amdgcn_cvt_pk_f32_fp8((int)RV.x, false); \
        v2f t1 = __builtin_amdgcn_cvt_pk_f32_fp8((int)RV.x, true);  \
        v2f t2 = __builtin_amdgcn_cvt_pk_f32_fp8((int)RV.y, false); \
        v2f t3 = __builtin_amdgcn_cvt_pk_f32_fp8((int)RV.y, true);  \
        v2f t4 = __builtin_amdgcn_cvt_pk_f32_fp8((int)RV.z, false); \
        v2f t5 = __builtin_amdgcn_cvt_pk_f32_fp8((int)RV.z, true);  \
        v2f t6 = __builtin_amdgcn_cvt_pk_f32_fp8((int)RV.w, false); \
        v2f t7 = __builtin_amdgcn_cvt_pk_f32_fp8((int)RV.w, true);  \
        acc[0]  = fmaf(W, t0.x, acc[0]);  acc[1]  = fmaf(W, t0.y, acc[1]);  \
        acc[2]  = fmaf(W, t1.x, acc[2]);  acc[3]  = fmaf(W, t1.y, acc[3]);  \
        acc[4]  = fmaf(W, t2.x, acc[4]);  acc[5]  = fmaf(W, t2.y, acc[5]);  \
        acc[6]  = fmaf(W, t3.x, acc[6]);  acc[7]  = fmaf(W, t3.y, acc[7]);  \
        acc[8]  = fmaf(W, t4.x, acc[8]);  acc[9]  = fmaf(W, t4.y, acc[9]);  \
        acc[10] = fmaf(W, t5.x, acc[10]); acc[11] = fmaf(W, t5.y, acc[11]); \
        acc[12] = fmaf(W, t6.x, acc[12]); acc[13] = fmaf(W, t6.y, acc[13]); \
        acc[14] = fmaf(W, t7.x, acc[14]); acc[15] = fmaf(W, t7.y, acc[15]); \
    } while (0)
        ACC16(r0, w0);
        ACC16(r1, w1);
        ACC16(r2, w2);
        ACC16(r3, w3);
#undef ACC16
        idx_cur = idx_nxt;
    }
    // merge the two edge-parity partials (lanes differing in bit 2)
#pragma unroll
    for (int q = 0; q < 16; ++q) acc[q] += __shfl_xor(acc[q], 4);
    if (rv) {
        float rs = rsqrtf(fmaxf((float)deg, 1.0f));
        // lane writes features [s*16 + e*8, s*16 + e*8 + 8): static-index select
        float v0 = e ? acc[8]  : acc[0];
        float v1 = e ? acc[9]  : acc[1];
        float v2 = e ? acc[10] : acc[2];
        float v3 = e ? acc[11] : acc[3];
        float v4 = e ? acc[12] : acc[4];
        float v5 = e ? acc[13] : acc[5];
        float v6 = e ? acc[14] : acc[6];
        float v7 = e ? acc[15] : acc[7];
        union { float4 f; __half2 h[4]; } o;
        o.h[0] = __floats2half2_rn(v0 * rs, v1 * rs);
        o.h[1] = __floats2half2_rn(v2 * rs, v3 * rs);
        o.h[2] = __floats2half2_rn(v4 * rs, v5 * rs);
        o.h[3] = __floats2half2_rn(v6 * rs, v7 * rs);
        *(float4*)(out + ((size_t)row << 6) + (s << 4) + (e << 3)) = o.f;
    }
}

// ---------------- fused GEMM + BN stats, spill-proof restructure (R6) ----------------
// R4/R5 post-mortem: acc[64]-per-thread spilled to scratch (VGPR_Count 64/68;
// 3.2GB scratch traffic at ~34TB/s L2 ~= the measured 84us). launch_bounds didn't
// lift the allocator's target. Fix: make the working set fit ANY target.
// Block = 256 = 4 waves; wave w owns output cols [w*16,w*16+16) (readfirstlane ->
// SGPR -> W-row reads stay s_load); lane l owns node blk*64+l (coalesced m reads).
// acc[16]+mreg[8] ~= 45 VGPR. Stats via 6-step shfl_xor butterfly (no 17KB LDS),
// lane 0 per wave does 16+16 slot-spread atomics; finalize tail unchanged.
__global__ void __launch_bounds__(256, 1)
k_gemm_stats(const __half* __restrict__ m, const float* __restrict__ W,
             const float* __restrict__ b, __half* __restrict__ out,
             float* __restrict__ ssum, float* __restrict__ ssq,
             const float* __restrict__ g, float* __restrict__ mu,
             float* __restrict__ coef, int* __restrict__ cnt, int N) {
    __shared__ int lastv;
    int tid = threadIdx.x;
    int w  = __builtin_amdgcn_readfirstlane(tid >> 6);   // wave id, force SGPR
    int l  = tid & 63;                                    // node lane
    int j0 = w << 4;                                      // column base (SGPR)
    int n = blockIdx.x * 64 + l;
    bool nv = n < N;
    int nc = nv ? n : N - 1;
    const float4* mrow4 = (const float4*)(m + (size_t)nc * FDIM);
    float acc[16];
#pragma unroll
    for (int j = 0; j < 16; ++j) acc[j] = b[j0 + j];     // wave-uniform -> s_load
    for (int k0 = 0; k0 < FDIM; k0 += 8) {
        union { float4 f; __half2 h[4]; } u;
        u.f = mrow4[k0 >> 3];                            // 8 halfs of this node's m-row
        float2 q0 = __half22float2(u.h[0]);
        float2 q1 = __half22float2(u.h[1]);
        float2 q2 = __half22float2(u.h[2]);
        float2 q3 = __half22float2(u.h[3]);
        float mreg[8] = {q0.x, q0.y, q1.x, q1.y, q2.x, q2.y, q3.x, q3.y};
#pragma unroll
        for (int k1 = 0; k1 < 8; ++k1) {
            const float* Wrow = W + (k0 + k1) * FDIM + j0;   // wave-uniform -> s_load
#pragma unroll
            for (int j = 0; j < 16; ++j)
                acc[j] = fmaf(mreg[k1], Wrow[j], acc[j]);
        }
    }
    if (nv) {
        float4* orow = (float4*)(out + (size_t)n * FDIM + j0);   // 32B aligned
        union { __half2 h[4]; float4 f; } o;
        o.h[0] = __floats2half2_rn(acc[0], acc[1]);
        o.h[1] = __floats2half2_rn(acc[2], acc[3]);
        o.h[2] = __floats2half2_rn(acc[4], acc[5]);
        o.h[3] = __floats2half2_rn(acc[6], acc[7]);
        orow[0] = o.f;
        o.h[0] = __floats2half2_rn(acc[8], acc[9]);
        o.h[1] = __floats2half2_rn(acc[10], acc[11]);
        o.h[2] = __floats2half2_rn(acc[12], acc[13]);
        o.h[3] = __floats2half2_rn(acc[14], acc[15]);
        orow[1] = o.f;
    }
    // ---- stats: butterfly-reduce sum & sumsq over the 64 lanes (nodes) ----
    float sq[16];
#pragma unroll
    for (int j = 0; j < 16; ++j) {
        float v = nv ? acc[j] : 0.f;
        acc[j] = v;
        sq[j] = v * v;
    }
#pragma unroll
    for (int off = 1; off < 64; off <<= 1) {
#pragma unroll
        for (int j = 0; j < 16; ++j) {
            acc[j] += __shfl_xor(acc[j], off);
            sq[j]  += __shfl_xor(sq[j], off);
        }
    }
    int slot = (blockIdx.x & (NSLOT - 1)) << 6;
    if (l == 0) {
#pragma unroll
        for (int j = 0; j < 16; ++j) {
            atomicAdd(&ssum[slot + j0 + j], acc[j]);
            atomicAdd(&ssq[slot + j0 + j], sq[j]);
        }
    }
    __syncthreads();
    if (tid == 0)
        lastv = (__hip_atomic_fetch_add(cnt, 1, __ATOMIC_ACQ_REL,
                                        __HIP_MEMORY_SCOPE_AGENT) == (int)gridDim.x - 1);
    __syncthreads();
    if (lastv && tid < 64) {
        float s2 = 0.f, q2 = 0.f;
#pragma unroll
        for (int p = 0; p < NSLOT; ++p) {
            s2 += __hip_atomic_load(&ssum[(p << 6) + tid], __ATOMIC_RELAXED,
                                    __HIP_MEMORY_SCOPE_AGENT);
            q2 += __hip_atomic_load(&ssq[(p << 6) + tid], __ATOMIC_RELAXED,
                                    __HIP_MEMORY_SCOPE_AGENT);
        }
        float mm = s2 / (float)N;
        float var = q2 / (float)N - mm * mm;
        mu[tid] = mm;
        coef[tid] = rsqrtf(var + EPS) * g[tid];
    }
}

// ---------------- out8 = fp8(relu((h-mu)*coef+be) * rsqrt(max(degO,1))) ----------------
__global__ void k_bnrelu_scale(const float2* __restrict__ h, const float* __restrict__ mu,
                               const float* __restrict__ coef, const float* __restrict__ be,
                               const int* __restrict__ degO, int* __restrict__ out8, int n4) {
    int i = blockIdx.x * blockDim.x + threadIdx.x;
    if (i < n4) {
        int n = i >> 4;
        int j4 = (i & 15) << 2;
        float rs = rsqrtf((float)max(degO[n], 1));
        union { __half2 hh[2]; float2 f; } u;
        u.f = h[i];
        float2 v0 = __half22float2(u.hh[0]);
        float2 v1 = __half22float2(u.hh[1]);
        float r0 = fmaxf((v0.x - mu[j4 + 0]) * coef[j4 + 0] + be[j4 + 0], 0.f) * rs;
        float r1 = fmaxf((v0.y - mu[j4 + 1]) * coef[j4 + 1] + be[j4 + 1], 0.f) * rs;
        float r2 = fmaxf((v1.x - mu[j4 + 2]) * coef[j4 + 2] + be[j4 + 2], 0.f) * rs;
        float r3 = fmaxf((v1.y - mu[j4 + 3]) * coef[j4 + 3] + be[j4 + 3], 0.f) * rs;
        int wv = __builtin_amdgcn_cvt_pk_fp8_f32(r0, r1, 0, false);
        wv     = __builtin_amdgcn_cvt_pk_fp8_f32(r2, r3, wv, true);
        out8[i] = wv;                      // 4 fp8 per thread, linear 4B writes
    }
}

// ---------------- relu(bn(h)) channel-sum (slot-spread) + last-block classifier -------
__global__ void k_bnmean_fin(const __half* __restrict__ h, const float* __restrict__ mu,
                             const float* __restrict__ coef, const float* __restrict__ be,
                             float* __restrict__ hsum, const float* __restrict__ Wc,
                             const float* __restrict__ bc, float* __restrict__ out,
                             int* __restrict__ cnt, int N) {
    __shared__ float red[4][64];
    __shared__ float cls[128];
    __shared__ int lastv;
    int tid = threadIdx.x;
    int sl = tid & 7;
    int nl = tid >> 3;
    int j8 = sl * 8;
    float m_[8], c_[8], b_[8];
#pragma unroll
    for (int p = 0; p < 8; ++p) { m_[p] = mu[j8 + p]; c_[p] = coef[j8 + p]; b_[p] = be[j8 + p]; }
    float s[8] = {0.f,0.f,0.f,0.f,0.f,0.f,0.f,0.f};
    int stride = gridDim.x * 32;
    for (int n = blockIdx.x * 32 + nl; n < N; n += stride) {
        union { float4 f; __half2 hh[4]; } u;
        u.f = ((const float4*)(h + ((size_t)n << 6)))[sl];
#pragma unroll
        for (int p = 0; p < 4; ++p) {
            float2 v = __half22float2(u.hh[p]);
            s[2*p]   += fmaxf((v.x - m_[2*p])   * c_[2*p]   + b_[2*p],   0.f);
            s[2*p+1] += fmaxf((v.y - m_[2*p+1]) * c_[2*p+1] + b_[2*p+1], 0.f);
        }
    }
#pragma unroll
    for (int off = 8; off < 64; off <<= 1) {
#pragma unroll
        for (int p = 0; p < 8; ++p) s[p] += __shfl_xor(s[p], off);
    }
    int wv = tid >> 6, lane = tid & 63;
    if (lane < 8) {
#pragma unroll
        for (int p = 0; p < 8; ++p) red[wv][lane * 8 + p] = s[p];
    }
    __syncthreads();
    int slot = (blockIdx.x & (NSLOT - 1)) << 6;
    if (tid < 64)
        atomicAdd(&hsum[slot + tid], red[0][tid] + red[1][tid] + red[2][tid] + red[3][tid]);
    __syncthreads();
    if (tid == 0)
        lastv = (__hip_atomic_fetch_add(cnt, 1, __ATOMIC_ACQ_REL,
                                        __HIP_MEMORY_SCOPE_AGENT) == (int)gridDim.x - 1);
    __syncthreads();
    if (lastv) {
        if (tid < 64) {
            float hg = 0.f;
#pragma unroll
            for (int p = 0; p < NSLOT; ++p)
                hg += __hip_atomic_load(&hsum[(p << 6) + tid], __ATOMIC_RELAXED,
                                        __HIP_MEMORY_SCOPE_AGENT);
            hg /= (float)N;
            cls[tid]      = hg * Wc[tid * 2 + 0];
            cls[64 + tid] = hg * Wc[tid * 2 + 1];
        }
        __syncthreads();
        if (tid == 0) {
            float a = 0.f, bv = 0.f;
            for (int k = 0; k < 64; ++k) { a += cls[k]; bv += cls[64 + k]; }
            out[0] = a + bc[0];
            out[1] = bv + bc[1];
        }
    }
}

extern "C" void kernel_launch(void* const* d_in, const int* in_sizes, int n_in,
                              void* d_out, int out_size, void* d_ws, size_t ws_size,
                              hipStream_t stream) {
    const float* x   = (const float*)d_in[0];
    const int*   src = (const int*)d_in[1];
    const int*   dst = (const int*)d_in[2];
    const float* W1  = (const float*)d_in[3];
    const float* b1  = (const float*)d_in[4];
    const float* g1  = (const float*)d_in[5];
    const float* be1 = (const float*)d_in[6];
    const float* W2  = (const float*)d_in[7];
    const float* b2  = (const float*)d_in[8];
    const float* g2  = (const float*)d_in[9];
    const float* be2 = (const float*)d_in[10];
    const float* Wc  = (const float*)d_in[11];
    const float* bc  = (const float*)d_in[12];
    float* out = (float*)d_out;

    const int N = in_sizes[0] / FDIM;   // 100000
    const int E = in_sizes[1];          // 1600000

    // ---- workspace layout (unchanged offsets; buf8 appended at end) ----
    char* w = (char*)d_ws;
    __half* bufA   = (__half*)w;                                  // N*64 halfs (12.8 MB)
    __half* bufB   = bufA + (size_t)N * FDIM;                     // N*64 halfs
    int*   csr_src = (int*)(bufB + (size_t)N * FDIM);             // E int
    int*   degO    = csr_src + E;                                 // N int
    int*   rowptr  = degO + N;                                    // N+2 int
    int*   histS   = rowptr + N + 2;                              // RB*NBUCK int
    int*   histD   = histS + RB * NBUCK;                          // RB*NBUCK int
    int*   baseS   = histD + RB * NBUCK;                          // NBUCK+1
    int*   baseD   = baseS + NBUCK + 1;                           // NBUCK+1
    int*   psumS   = baseD + NBUCK + 1;                           // (RB/GRP)*NBUCK
    int*   psumD   = psumS + (RB / GRP) * NBUCK;                  // (RB/GRP)*NBUCK
    int*   grpbaseS= psumD + (RB / GRP) * NBUCK;                  // (RB/GRP)*NBUCK
    int*   grpbaseD= grpbaseS + (RB / GRP) * NBUCK;               // (RB/GRP)*NBUCK
    float* stats   = (float*)(grpbaseD + (RB / GRP) * NBUCK);     // 4096 f } memset
    unsigned char* tmpS = (unsigned char*)(stats + 4096);         // E bytes (dedicated)
    unsigned char* buf8 = tmpS + E;                               // N*64 fp8 (6.4 MB), 16B-aligned
    int*           tmpD = (int*)bufB;                             // E int, aliases bufB (dead)

    float* sum1  = stats + 0;            // [NSLOT][64] = 512
    float* sq1   = stats + 512;          // 512
    float* sum2  = stats + 1024;         // 512
    float* sq2   = stats + 1536;         // 512
    float* hsum  = stats + 2048;         // 512
    float* mu1   = stats + 2560;
    float* coef1 = stats + 2624;
    float* mu2   = stats + 2688;
    float* coef2 = stats + 2752;
    int*   cnt1  = (int*)(stats + 2816);
    int*   cnt2  = (int*)(stats + 2817);
    int*   cnt3  = (int*)(stats + 2818);

    const int n4 = N * (FDIM / 4);
    const int spmm8_blocks = ((N + 7) / 8 + 3) / 4;       // 8 rows/wave, 4 waves/block
    const int gemm_blocks = (N + 63) / 64;                // 64 nodes per 256-thread block
    const int nbuck_active = (N + LOWMASK) >> LOWB;       // 782 for N=100000
    const int chunk = ((E + RB - 1) / RB + 3) & ~3;       // per-block edges, mult of 4

    hipMemsetAsync(stats, 0, 4096 * 4, stream);

    k_hist<<<RB, RT, 0, stream>>>(src, dst, histS, histD, E, chunk);
    k_scanA<<<2 * (RB / GRP) * 4, 256, 0, stream>>>(histS, histD, psumS, psumD);
    k_scanB<<<2, NBUCK, 0, stream>>>(psumS, baseS, grpbaseS, psumD, baseD, grpbaseD);
    k_bucket<<<RB, RT, 0, stream>>>(src, dst, histS, histD, grpbaseS, grpbaseD,
                                    tmpS, tmpD, E, chunk);
    k_fine<<<2 * nbuck_active, 256, 0, stream>>>(tmpD, baseD, csr_src, rowptr,
                                                 tmpS, baseS, degO, x, buf8, N, nbuck_active);

    // layer 1: fp8 gather -> fp16 m (bufB); fused gemm+stats: bufB -> bufA + mu1/coef1
    k_spmm8<<<spmm8_blocks, 256, 0, stream>>>(buf8, rowptr, csr_src, bufB, N);
    k_gemm_stats<<<gemm_blocks, 256, 0, stream>>>(bufB, W1, b1, bufA, sum1, sq1,
                                                  g1, mu1, coef1, cnt1, N);
    k_bnrelu_scale<<<(n4 + 255) / 256, 256, 0, stream>>>((const float2*)bufA, mu1, coef1, be1,
                                                         degO, (int*)buf8, n4);
    // layer 2
    k_spmm8<<<spmm8_blocks, 256, 0, stream>>>(buf8, rowptr, csr_src, bufB, N);
    k_gemm_stats<<<gemm_blocks, 256, 0, stream>>>(bufB, W2, b2, bufA, sum2, sq2,
                                                  g2, mu2, coef2, cnt2, N);
    k_bnmean_fin<<<256, 256, 0, stream>>>(bufA, mu2, coef2, be2, hsum, Wc, bc, out, cnt3, N);
}

// Round 7
// 279.592 us; speedup vs baseline: 1.5725x; 1.5725x over previous
//
#include <hip/hip_runtime.h>
#include <hip/hip_fp16.h>

#define FDIM 64
#define EPS 1e-5f
#define NBUCK 1024     // coarse buckets = high bits of 17-bit id
#define LOWB 7
#define LOWMASK 127
#define RB 256         // radix blocks
#define RT 1024        // radix threads per block
#define GRP 16         // rows per scan group (RB/GRP groups)
#define NSLOT 8        // accumulator slots to spread atomic RMW lines

typedef float v2f __attribute__((ext_vector_type(2)));

// ---------------- per-block coarse histograms of src>>7 and dst>>7 ----------------
__global__ void k_hist(const int* __restrict__ src, const int* __restrict__ dst,
                       int* __restrict__ histS, int* __restrict__ histD, int E, int chunk) {
    __shared__ int hs[NBUCK], hd[NBUCK];
    int tid = threadIdx.x;            // RT == NBUCK == 1024
    hs[tid] = 0; hd[tid] = 0;
    __syncthreads();
    int b = blockIdx.x;
    int beg = b * chunk;
    int end = min(E, beg + chunk);
    int i = beg + tid * 4;
    for (; i + 3 < end; i += RT * 4) {
        int4 s = *(const int4*)(src + i);
        int4 d = *(const int4*)(dst + i);
        atomicAdd(&hs[s.x >> LOWB], 1); atomicAdd(&hd[d.x >> LOWB], 1);
        atomicAdd(&hs[s.y >> LOWB], 1); atomicAdd(&hd[d.y >> LOWB], 1);
        atomicAdd(&hs[s.z >> LOWB], 1); atomicAdd(&hd[d.z >> LOWB], 1);
        atomicAdd(&hs[s.w >> LOWB], 1); atomicAdd(&hd[d.w >> LOWB], 1);
    }
    if (i < end) {
        for (int j = i; j < end && j < i + 4; ++j) {
            atomicAdd(&hs[src[j] >> LOWB], 1);
            atomicAdd(&hd[dst[j] >> LOWB], 1);
        }
    }
    __syncthreads();
    histS[b * NBUCK + tid] = hs[tid];
    histD[b * NBUCK + tid] = hd[tid];
}

// ---------------- scan A: per-group column partial sums (fully parallel) ----------------
__global__ void k_scanA(const int* __restrict__ histS, const int* __restrict__ histD,
                        int* __restrict__ psumS, int* __restrict__ psumD) {
    int bid = blockIdx.x;
    int m = bid >> 6;                 // 0 = S, 1 = D
    int g = (bid >> 2) & (RB / GRP - 1);
    int c = bid & 3;
    const int* hist = m ? histD : histS;
    int* psum = m ? psumD : psumS;
    int k = c * 256 + threadIdx.x;
    int s = 0;
#pragma unroll
    for (int r = 0; r < GRP; ++r)
        s += hist[(g * GRP + r) * NBUCK + k];
    psum[g * NBUCK + k] = s;
}

// ---------------- scan B: group-level scan + bucket-base scan ----------------
__global__ void k_scanB(const int* __restrict__ psumS, int* __restrict__ baseS,
                        int* __restrict__ grpbaseS,
                        const int* __restrict__ psumD, int* __restrict__ baseD,
                        int* __restrict__ grpbaseD) {
    const int* psum = blockIdx.x ? psumD : psumS;
    int* base    = blockIdx.x ? baseD : baseS;
    int* grpbase = blockIdx.x ? grpbaseD : grpbaseS;
    __shared__ int s[NBUCK];
    int k = threadIdx.x;
    int ge[RB / GRP];
    int run = 0;
#pragma unroll
    for (int g = 0; g < RB / GRP; ++g) { ge[g] = run; run += psum[g * NBUCK + k]; }
    s[k] = run;
    __syncthreads();
    for (int off = 1; off < NBUCK; off <<= 1) {
        int t = (k >= off) ? s[k - off] : 0;
        __syncthreads();
        s[k] += t;
        __syncthreads();
    }
    int excl = (k > 0) ? s[k - 1] : 0;
    base[k] = excl;
    if (k == NBUCK - 1) base[NBUCK] = s[NBUCK - 1];
#pragma unroll
    for (int g = 0; g < RB / GRP; ++g)
        grpbase[g * NBUCK + k] = excl + ge[g];
}

// ---------------- coarse partition: LDS cursors per block, no global atomics ----------------
__global__ void k_bucket(const int* __restrict__ src, const int* __restrict__ dst,
                         const int* __restrict__ histS, const int* __restrict__ histD,
                         const int* __restrict__ grpbaseS, const int* __restrict__ grpbaseD,
                         unsigned char* __restrict__ tmpS, int* __restrict__ tmpD,
                         int E, int chunk) {
    __shared__ int curS[NBUCK], curD[NBUCK];
    int tid = threadIdx.x;
    int b = blockIdx.x;
    int g = b / GRP;
    int rs = 0, rd = 0;
    for (int r = g * GRP; r < b; ++r) {
        rs += histS[r * NBUCK + tid];
        rd += histD[r * NBUCK + tid];
    }
    curS[tid] = grpbaseS[g * NBUCK + tid] + rs;
    curD[tid] = grpbaseD[g * NBUCK + tid] + rd;
    __syncthreads();
    int beg = b * chunk;
    int end = min(E, beg + chunk);
    int i = beg + tid * 4;
    for (; i + 3 < end; i += RT * 4) {
        int4 s = *(const int4*)(src + i);
        int4 d = *(const int4*)(dst + i);
        int p;
        p = atomicAdd(&curS[s.x >> LOWB], 1); tmpS[p] = (unsigned char)(s.x & LOWMASK);
        p = atomicAdd(&curS[s.y >> LOWB], 1); tmpS[p] = (unsigned char)(s.y & LOWMASK);
        p = atomicAdd(&curS[s.z >> LOWB], 1); tmpS[p] = (unsigned char)(s.z & LOWMASK);
        p = atomicAdd(&curS[s.w >> LOWB], 1); tmpS[p] = (unsigned char)(s.w & LOWMASK);
        p = atomicAdd(&curD[d.x >> LOWB], 1); tmpD[p] = (s.x << LOWB) | (d.x & LOWMASK);
        p = atomicAdd(&curD[d.y >> LOWB], 1); tmpD[p] = (s.y << LOWB) | (d.y & LOWMASK);
        p = atomicAdd(&curD[d.z >> LOWB], 1); tmpD[p] = (s.z << LOWB) | (d.z & LOWMASK);
        p = atomicAdd(&curD[d.w >> LOWB], 1); tmpD[p] = (s.w << LOWB) | (d.w & LOWMASK);
    }
    if (i < end) {
        for (int j = i; j < end && j < i + 4; ++j) {
            int sv = src[j], dv = dst[j];
            int p = atomicAdd(&curS[sv >> LOWB], 1);
            tmpS[p] = (unsigned char)(sv & LOWMASK);
            p = atomicAdd(&curD[dv >> LOWB], 1);
            tmpD[p] = (sv << LOWB) | (dv & LOWMASK);
        }
    }
}

// ---------------- merged fine pass (one dispatch, two jobs running concurrently) ------
__global__ void k_fine(const int* __restrict__ tmpD, const int* __restrict__ baseD,
                       int* __restrict__ csr_src, int* __restrict__ rowptr,
                       const unsigned char* __restrict__ tmpS, const int* __restrict__ baseS,
                       int* __restrict__ degO, const float* __restrict__ x,
                       unsigned char* __restrict__ buf8, int N, int nbuck) {
    __shared__ int hist[128];
    __shared__ int scanv[128];
    int tid = threadIdx.x;
    if (blockIdx.x < nbuck) {
        int b = blockIdx.x;
        int s0 = baseD[b];
        int s1 = baseD[b + 1];
        if (tid < 128) hist[tid] = 0;
        __syncthreads();
        for (int i = s0 + tid; i < s1; i += 256)
            atomicAdd(&hist[tmpD[i] & LOWMASK], 1);
        __syncthreads();
        int mine = (tid < 128) ? hist[tid] : 0;
        if (tid < 128) scanv[tid] = mine;
        __syncthreads();
        for (int off = 1; off < 128; off <<= 1) {
            int t = (tid < 128 && tid >= off) ? scanv[tid - off] : 0;
            __syncthreads();
            if (tid < 128) scanv[tid] += t;
            __syncthreads();
        }
        if (tid < 128) {
            int excl = scanv[tid] - mine;       // exclusive scan
            int d = (b << LOWB) + tid;
            if (d <= N) rowptr[d] = s0 + excl;  // covers rowptr[N]=E too
            hist[tid] = excl;                   // LDS cursors
        }
        __syncthreads();
        for (int i = s0 + tid; i < s1; i += 256) {
            int p = tmpD[i];
            int pos = atomicAdd(&hist[p & LOWMASK], 1);
            csr_src[s0 + pos] = p >> LOWB;
        }
    } else {
        int b = blockIdx.x - nbuck;
        int s0 = baseS[b];
        int s1 = baseS[b + 1];
        if (tid < 128) hist[tid] = 0;
        __syncthreads();
        for (int i = s0 + tid; i < s1; i += 256)
            atomicAdd(&hist[tmpS[i]], 1);
        __syncthreads();
        if (tid < 128) {
            int d = (b << LOWB) + tid;
            if (d < N) degO[d] = hist[tid];
        }
        // scale x rows, quantize to fp8: thread = (node, half-row part of 32 feats)
        int node = (b << LOWB) + (tid >> 1);
        if (node < N) {
            float rs = rsqrtf((float)max(hist[tid >> 1], 1));
            int part = tid & 1;                 // feats [part*32, part*32+32)
            const float4* xr = (const float4*)(x + (size_t)node * FDIM) + part * 8;
            int4* orow = (int4*)(buf8 + (size_t)node * FDIM + part * 32); // 2 int4 = 32 fp8
            int wbuf[8];
#pragma unroll
            for (int q = 0; q < 4; ++q) {
                float4 a = xr[2 * q];
                float4 c = xr[2 * q + 1];
                int t = __builtin_amdgcn_cvt_pk_fp8_f32(a.x * rs, a.y * rs, 0, false);
                t     = __builtin_amdgcn_cvt_pk_fp8_f32(a.z * rs, a.w * rs, t, true);
                wbuf[2 * q] = t;
                t = __builtin_amdgcn_cvt_pk_fp8_f32(c.x * rs, c.y * rs, 0, false);
                t = __builtin_amdgcn_cvt_pk_fp8_f32(c.z * rs, c.w * rs, t, true);
                wbuf[2 * q + 1] = t;
            }
            orow[0] = make_int4(wbuf[0], wbuf[1], wbuf[2], wbuf[3]);
            orow[1] = make_int4(wbuf[4], wbuf[5], wbuf[6], wbuf[7]);
        }
    }
}

// ---------------- CSR SpMM: 8 rows/wave, 16B/lane gather = 4 requests/edge ------------
// (R3 remap, kept: 4 lanes cover a 64B fp8 row; 4 req/edge instead of 8.)
__global__ void k_spmm8(const unsigned char* __restrict__ hin, const int* __restrict__ rowptr,
                        const int* __restrict__ csr_src, __half* __restrict__ out, int N) {
    int wid = (blockIdx.x * blockDim.x + threadIdx.x) >> 6;
    int lane = threadIdx.x & 63;
    int g  = lane >> 3;          // output row within wave (8 rows)
    int sl = lane & 7;           // idx slot (8 idx per row, layout unchanged)
    int e  = (lane >> 2) & 1;    // edge parity
    int s  = lane & 3;           // 16B slice of the 64B row
    int row = wid * 8 + g;
    bool rv = row < N;
    int start = rv ? rowptr[row] : 0;
    int end   = rv ? rowptr[row + 1] : 0;
    int deg = end - start;
    int md = deg;
    md = max(md, __shfl_xor(md, 8));
    md = max(md, __shfl_xor(md, 16));
    md = max(md, __shfl_xor(md, 32));
    float acc[16];
#pragma unroll
    for (int q = 0; q < 16; ++q) acc[q] = 0.f;
    int safe = (deg > 0) ? end - 1 : 0;
    int a0 = start + sl;
    int idx_cur = csr_src[(a0 < end) ? a0 : safe];   // in flight across setup
    for (int it = 0; it < md; it += 8) {
        int idx_nxt = 0;
        if (it + 8 < md) {
            int a = start + it + 8 + sl;
            idx_nxt = csr_src[(a < end) ? a : safe]; // prefetch next block's indices
        }
        int b0 = __shfl(idx_cur, (g << 3) + e);
        int b1 = __shfl(idx_cur, (g << 3) + e + 2);
        int b2 = __shfl(idx_cur, (g << 3) + e + 4);
        int b3 = __shfl(idx_cur, (g << 3) + e + 6);
        uint4 r0 = ((const uint4*)(hin + ((size_t)b0 << 6)))[s];
        uint4 r1 = ((const uint4*)(hin + ((size_t)b1 << 6)))[s];
        uint4 r2 = ((const uint4*)(hin + ((size_t)b2 << 6)))[s];
        uint4 r3 = ((const uint4*)(hin + ((size_t)b3 << 6)))[s];
        __builtin_amdgcn_sched_barrier(0);   // pin: all 4 gathers issue before use
        float w0 = (it + e     < deg) ? 1.f : 0.f;
        float w1 = (it + e + 2 < deg) ? 1.f : 0.f;
        float w2 = (it + e + 4 < deg) ? 1.f : 0.f;
        float w3 = (it + e + 6 < deg) ? 1.f : 0.f;
#define ACC16(RV, W) do { \
        v2f t0 = __builtin_amdgcn_cvt_pk_f32_fp8((int)RV.x, false); \
        v2f t1 = __builtin_amdgcn_cvt_pk_f32_fp8((int)RV.x, true);  \
        v2f t2 = __builtin_amdgcn_cvt_pk_f32_fp8((int)RV.y, false); \
        v2f t3 = __builtin_amdgcn_cvt_pk_f32_fp8((int)RV.y, true);  \
        v2f t4 = __builtin_amdgcn_cvt_pk_f32_fp8((int)RV.z, false); \
        v2f t5 = __builtin_amdgcn_cvt_pk_f32_fp8((int)RV.z, true);  \
        v2f t6 = __builtin_amdgcn_cvt_pk_f32_fp8((int)RV.w, false); \
        v2f t7 = __builtin_amdgcn_cvt_pk_f32_fp8((int)RV.w, true);  \
        acc[0]  = fmaf(W, t0.x, acc[0]);  acc[1]  = fmaf(W, t0.y, acc[1]);  \
        acc[2]  = fmaf(W, t1.x, acc[2]);  acc[3]  = fmaf(W, t1.y, acc[3]);  \
        acc[4]  = fmaf(W, t2.x, acc[4]);  acc[5]  = fmaf(W, t2.y, acc[5]);  \
        acc[6]  = fmaf(W, t3.x, acc[6]);  acc[7]  = fmaf(W, t3.y, acc[7]);  \
        acc[8]  = fmaf(W, t4.x, acc[8]);  acc[9]  = fmaf(W, t4.y, acc[9]);  \
        acc[10] = fmaf(W, t5.x, acc[10]); acc[11] = fmaf(W, t5.y, acc[11]); \
        acc[12] = fmaf(W, t6.x, acc[12]); acc[13] = fmaf(W, t6.y, acc[13]); \
        acc[14] = fmaf(W, t7.x, acc[14]); acc[15] = fmaf(W, t7.y, acc[15]); \
    } while (0)
        ACC16(r0, w0);
        ACC16(r1, w1);
        ACC16(r2, w2);
        ACC16(r3, w3);
#undef ACC16
        idx_cur = idx_nxt;
    }
    // merge the two edge-parity partials (lanes differing in bit 2)
#pragma unroll
    for (int q = 0; q < 16; ++q) acc[q] += __shfl_xor(acc[q], 4);
    if (rv) {
        float rs = rsqrtf(fmaxf((float)deg, 1.0f));
        // lane writes features [s*16 + e*8, s*16 + e*8 + 8): static-index select
        float v0 = e ? acc[8]  : acc[0];
        float v1 = e ? acc[9]  : acc[1];
        float v2 = e ? acc[10] : acc[2];
        float v3 = e ? acc[11] : acc[3];
        float v4 = e ? acc[12] : acc[4];
        float v5 = e ? acc[13] : acc[5];
        float v6 = e ? acc[14] : acc[6];
        float v7 = e ? acc[15] : acc[7];
        union { float4 f; __half2 h[4]; } o;
        o.h[0] = __floats2half2_rn(v0 * rs, v1 * rs);
        o.h[1] = __floats2half2_rn(v2 * rs, v3 * rs);
        o.h[2] = __floats2half2_rn(v4 * rs, v5 * rs);
        o.h[3] = __floats2half2_rn(v6 * rs, v7 * rs);
        *(float4*)(out + ((size_t)row << 6) + (s << 4) + (e << 3)) = o.f;
    }
}

// ---------------- register GEMM: 1 thread = 1 node (R2 version — known non-spilling) --
__global__ void k_gemm_reg(const __half* __restrict__ m, const float* __restrict__ W,
                           const float* __restrict__ b, __half* __restrict__ out, int N) {
    int n = blockIdx.x * blockDim.x + threadIdx.x;
    if (n >= N) return;
    const __half2* mrow = (const __half2*)(m + (size_t)n * FDIM);
    float acc[FDIM];
#pragma unroll
    for (int j = 0; j < FDIM; ++j) acc[j] = b[j];        // b[j] wave-uniform -> s_load
    for (int k0 = 0; k0 < FDIM; k0 += 8) {
        float2 f0 = __half22float2(mrow[(k0 >> 1) + 0]);
        float2 f1 = __half22float2(mrow[(k0 >> 1) + 1]);
        float2 f2 = __half22float2(mrow[(k0 >> 1) + 2]);
        float2 f3 = __half22float2(mrow[(k0 >> 1) + 3]);
        float mreg[8] = {f0.x, f0.y, f1.x, f1.y, f2.x, f2.y, f3.x, f3.y};
#pragma unroll
        for (int k1 = 0; k1 < 8; ++k1) {
            const float* Wrow = W + (k0 + k1) * FDIM;    // wave-uniform row -> s_load
#pragma unroll
            for (int j = 0; j < FDIM; ++j)
                acc[j] = fmaf(mreg[k1], Wrow[j], acc[j]);
        }
    }
    float4* orow = (float4*)(out + (size_t)n * FDIM);
#pragma unroll
    for (int j = 0; j < FDIM; j += 8) {
        union { __half2 h[4]; float4 f; } u;
        u.h[0] = __floats2half2_rn(acc[j + 0], acc[j + 1]);
        u.h[1] = __floats2half2_rn(acc[j + 2], acc[j + 3]);
        u.h[2] = __floats2half2_rn(acc[j + 4], acc[j + 5]);
        u.h[3] = __floats2half2_rn(acc[j + 6], acc[j + 7]);
        orow[j >> 3] = u.f;
    }
}

// ---------------- BN stats: slot-spread atomics + last-block finalize (R2 version) ----
__global__ void k_stats_fin(const __half* __restrict__ h, float* __restrict__ ssum,
                            float* __restrict__ ssq, const float* __restrict__ g,
                            float* __restrict__ mu, float* __restrict__ coef,
                            int* __restrict__ cnt, int N) {
    __shared__ float red[4][128];
    __shared__ int lastv;
    int tid = threadIdx.x;
    int sl = tid & 7;
    int nl = tid >> 3;
    float s[8] = {0.f,0.f,0.f,0.f,0.f,0.f,0.f,0.f};
    float q[8] = {0.f,0.f,0.f,0.f,0.f,0.f,0.f,0.f};
    int stride = gridDim.x * 32;
    for (int n = blockIdx.x * 32 + nl; n < N; n += stride) {
        union { float4 f; __half2 hh[4]; } u;
        u.f = ((const float4*)(h + ((size_t)n << 6)))[sl];
#pragma unroll
        for (int p = 0; p < 4; ++p) {
            float2 v = __half22float2(u.hh[p]);
            s[2*p]   += v.x; q[2*p]   += v.x * v.x;
            s[2*p+1] += v.y; q[2*p+1] += v.y * v.y;
        }
    }
#pragma unroll
    for (int off = 8; off < 64; off <<= 1) {
#pragma unroll
        for (int p = 0; p < 8; ++p) {
            s[p] += __shfl_xor(s[p], off);
            q[p] += __shfl_xor(q[p], off);
        }
    }
    int wv = tid >> 6, lane = tid & 63;
    if (lane < 8) {
#pragma unroll
        for (int p = 0; p < 8; ++p) {
            red[wv][lane * 8 + p] = s[p];
            red[wv][64 + lane * 8 + p] = q[p];
        }
    }
    __syncthreads();
    int slot = (blockIdx.x & (NSLOT - 1)) << 6;
    if (tid < 128) {
        float v = red[0][tid] + red[1][tid] + red[2][tid] + red[3][tid];
        if (tid < 64) atomicAdd(&ssum[slot + tid], v);
        else          atomicAdd(&ssq[slot + tid - 64], v);
    }
    __syncthreads();
    if (tid == 0)
        lastv = (__hip_atomic_fetch_add(cnt, 1, __ATOMIC_ACQ_REL,
                                        __HIP_MEMORY_SCOPE_AGENT) == (int)gridDim.x - 1);
    __syncthreads();
    if (lastv && tid < 64) {
        float sv = 0.f, qv = 0.f;
#pragma unroll
        for (int p = 0; p < NSLOT; ++p) {
            sv += __hip_atomic_load(&ssum[(p << 6) + tid], __ATOMIC_RELAXED,
                                    __HIP_MEMORY_SCOPE_AGENT);
            qv += __hip_atomic_load(&ssq[(p << 6) + tid], __ATOMIC_RELAXED,
                                    __HIP_MEMORY_SCOPE_AGENT);
        }
        float m = sv / (float)N;
        float var = qv / (float)N - m * m;
        mu[tid] = m;
        coef[tid] = rsqrtf(var + EPS) * g[tid];
    }
}

// ---------------- out8 = fp8(relu((h-mu)*coef+be) * rsqrt(max(degO,1))) ----------------
__global__ void k_bnrelu_scale(const float2* __restrict__ h, const float* __restrict__ mu,
                               const float* __restrict__ coef, const float* __restrict__ be,
                               const int* __restrict__ degO, int* __restrict__ out8, int n4) {
    int i = blockIdx.x * blockDim.x + threadIdx.x;
    if (i < n4) {
        int n = i >> 4;
        int j4 = (i & 15) << 2;
        float rs = rsqrtf((float)max(degO[n], 1));
        union { __half2 hh[2]; float2 f; } u;
        u.f = h[i];
        float2 v0 = __half22float2(u.hh[0]);
        float2 v1 = __half22float2(u.hh[1]);
        float r0 = fmaxf((v0.x - mu[j4 + 0]) * coef[j4 + 0] + be[j4 + 0], 0.f) * rs;
        float r1 = fmaxf((v0.y - mu[j4 + 1]) * coef[j4 + 1] + be[j4 + 1], 0.f) * rs;
        float r2 = fmaxf((v1.x - mu[j4 + 2]) * coef[j4 + 2] + be[j4 + 2], 0.f) * rs;
        float r3 = fmaxf((v1.y - mu[j4 + 3]) * coef[j4 + 3] + be[j4 + 3], 0.f) * rs;
        int wv = __builtin_amdgcn_cvt_pk_fp8_f32(r0, r1, 0, false);
        wv     = __builtin_amdgcn_cvt_pk_fp8_f32(r2, r3, wv, true);
        out8[i] = wv;                      // 4 fp8 per thread, linear 4B writes
    }
}

// ---------------- relu(bn(h)) channel-sum (slot-spread) + last-block classifier -------
__global__ void k_bnmean_fin(const __half* __restrict__ h, const float* __restrict__ mu,
                             const float* __restrict__ coef, const float* __restrict__ be,
                             float* __restrict__ hsum, const float* __restrict__ Wc,
                             const float* __restrict__ bc, float* __restrict__ out,
                             int* __restrict__ cnt, int N) {
    __shared__ float red[4][64];
    __shared__ float cls[128];
    __shared__ int lastv;
    int tid = threadIdx.x;
    int sl = tid & 7;
    int nl = tid >> 3;
    int j8 = sl * 8;
    float m_[8], c_[8], b_[8];
#pragma unroll
    for (int p = 0; p < 8; ++p) { m_[p] = mu[j8 + p]; c_[p] = coef[j8 + p]; b_[p] = be[j8 + p]; }
    float s[8] = {0.f,0.f,0.f,0.f,0.f,0.f,0.f,0.f};
    int stride = gridDim.x * 32;
    for (int n = blockIdx.x * 32 + nl; n < N; n += stride) {
        union { float4 f; __half2 hh[4]; } u;
        u.f = ((const float4*)(h + ((size_t)n << 6)))[sl];
#pragma unroll
        for (int p = 0; p < 4; ++p) {
            float2 v = __half22float2(u.hh[p]);
            s[2*p]   += fmaxf((v.x - m_[2*p])   * c_[2*p]   + b_[2*p],   0.f);
            s[2*p+1] += fmaxf((v.y - m_[2*p+1]) * c_[2*p+1] + b_[2*p+1], 0.f);
        }
    }
#pragma unroll
    for (int off = 8; off < 64; off <<= 1) {
#pragma unroll
        for (int p = 0; p < 8; ++p) s[p] += __shfl_xor(s[p], off);
    }
    int wv = tid >> 6, lane = tid & 63;
    if (lane < 8) {
#pragma unroll
        for (int p = 0; p < 8; ++p) red[wv][lane * 8 + p] = s[p];
    }
    __syncthreads();
    int slot = (blockIdx.x & (NSLOT - 1)) << 6;
    if (tid < 64)
        atomicAdd(&hsum[slot + tid], red[0][tid] + red[1][tid] + red[2][tid] + red[3][tid]);
    __syncthreads();
    if (tid == 0)
        lastv = (__hip_atomic_fetch_add(cnt, 1, __ATOMIC_ACQ_REL,
                                        __HIP_MEMORY_SCOPE_AGENT) == (int)gridDim.x - 1);
    __syncthreads();
    if (lastv) {
        if (tid < 64) {
            float hg = 0.f;
#pragma unroll
            for (int p = 0; p < NSLOT; ++p)
                hg += __hip_atomic_load(&hsum[(p << 6) + tid], __ATOMIC_RELAXED,
                                        __HIP_MEMORY_SCOPE_AGENT);
            hg /= (float)N;
            cls[tid]      = hg * Wc[tid * 2 + 0];
            cls[64 + tid] = hg * Wc[tid * 2 + 1];
        }
        __syncthreads();
        if (tid == 0) {
            float a = 0.f, bv = 0.f;
            for (int k = 0; k < 64; ++k) { a += cls[k]; bv += cls[64 + k]; }
            out[0] = a + bc[0];
            out[1] = bv + bc[1];
        }
    }
}

extern "C" void kernel_launch(void* const* d_in, const int* in_sizes, int n_in,
                              void* d_out, int out_size, void* d_ws, size_t ws_size,
                              hipStream_t stream) {
    const float* x   = (const float*)d_in[0];
    const int*   src = (const int*)d_in[1];
    const int*   dst = (const int*)d_in[2];
    const float* W1  = (const float*)d_in[3];
    const float* b1  = (const float*)d_in[4];
    const float* g1  = (const float*)d_in[5];
    const float* be1 = (const float*)d_in[6];
    const float* W2  = (const float*)d_in[7];
    const float* b2  = (const float*)d_in[8];
    const float* g2  = (const float*)d_in[9];
    const float* be2 = (const float*)d_in[10];
    const float* Wc  = (const float*)d_in[11];
    const float* bc  = (const float*)d_in[12];
    float* out = (float*)d_out;

    const int N = in_sizes[0] / FDIM;   // 100000
    const int E = in_sizes[1];          // 1600000

    // ---- workspace layout ----
    char* w = (char*)d_ws;
    __half* bufA   = (__half*)w;                                  // N*64 halfs (12.8 MB)
    __half* bufB   = bufA + (size_t)N * FDIM;                     // N*64 halfs
    int*   csr_src = (int*)(bufB + (size_t)N * FDIM);             // E int
    int*   degO    = csr_src + E;                                 // N int
    int*   rowptr  = degO + N;                                    // N+2 int
    int*   histS   = rowptr + N + 2;                              // RB*NBUCK int
    int*   histD   = histS + RB * NBUCK;                          // RB*NBUCK int
    int*   baseS   = histD + RB * NBUCK;                          // NBUCK+1
    int*   baseD   = baseS + NBUCK + 1;                           // NBUCK+1
    int*   psumS   = baseD + NBUCK + 1;                           // (RB/GRP)*NBUCK
    int*   psumD   = psumS + (RB / GRP) * NBUCK;                  // (RB/GRP)*NBUCK
    int*   grpbaseS= psumD + (RB / GRP) * NBUCK;                  // (RB/GRP)*NBUCK
    int*   grpbaseD= grpbaseS + (RB / GRP) * NBUCK;               // (RB/GRP)*NBUCK
    float* stats   = (float*)(grpbaseD + (RB / GRP) * NBUCK);     // 4096 f } memset
    unsigned char* tmpS = (unsigned char*)(stats + 4096);         // E bytes (dedicated)
    unsigned char* buf8 = tmpS + E;                               // N*64 fp8 (6.4 MB), 16B-aligned
    int*           tmpD = (int*)bufB;                             // E int, aliases bufB (dead)

    float* sum1  = stats + 0;            // [NSLOT][64] = 512
    float* sq1   = stats + 512;          // 512
    float* sum2  = stats + 1024;         // 512
    float* sq2   = stats + 1536;         // 512
    float* hsum  = stats + 2048;         // 512
    float* mu1   = stats + 2560;
    float* coef1 = stats + 2624;
    float* mu2   = stats + 2688;
    float* coef2 = stats + 2752;
    int*   cnt1  = (int*)(stats + 2816);
    int*   cnt2  = (int*)(stats + 2817);
    int*   cnt3  = (int*)(stats + 2818);

    const int n4 = N * (FDIM / 4);
    const int spmm8_blocks = ((N + 7) / 8 + 3) / 4;       // 8 rows/wave, 4 waves/block
    const int nbuck_active = (N + LOWMASK) >> LOWB;       // 782 for N=100000
    const int chunk = ((E + RB - 1) / RB + 3) & ~3;       // per-block edges, mult of 4

    hipMemsetAsync(stats, 0, 4096 * 4, stream);

    k_hist<<<RB, RT, 0, stream>>>(src, dst, histS, histD, E, chunk);
    k_scanA<<<2 * (RB / GRP) * 4, 256, 0, stream>>>(histS, histD, psumS, psumD);
    k_scanB<<<2, NBUCK, 0, stream>>>(psumS, baseS, grpbaseS, psumD, baseD, grpbaseD);
    k_bucket<<<RB, RT, 0, stream>>>(src, dst, histS, histD, grpbaseS, grpbaseD,
                                    tmpS, tmpD, E, chunk);
    k_fine<<<2 * nbuck_active, 256, 0, stream>>>(tmpD, baseD, csr_src, rowptr,
                                                 tmpS, baseS, degO, x, buf8, N, nbuck_active);

    // layer 1: fp8 gather -> fp16 m (bufB); gemm: bufB -> bufA; stats on bufA
    k_spmm8<<<spmm8_blocks, 256, 0, stream>>>(buf8, rowptr, csr_src, bufB, N);
    k_gemm_reg<<<(N + 63) / 64, 64, 0, stream>>>(bufB, W1, b1, bufA, N);
    k_stats_fin<<<256, 256, 0, stream>>>(bufA, sum1, sq1, g1, mu1, coef1, cnt1, N);
    k_bnrelu_scale<<<(n4 + 255) / 256, 256, 0, stream>>>((const float2*)bufA, mu1, coef1, be1,
                                                         degO, (int*)buf8, n4);
    // layer 2
    k_spmm8<<<spmm8_blocks, 256, 0, stream>>>(buf8, rowptr, csr_src, bufB, N);
    k_gemm_reg<<<(N + 63) / 64, 64, 0, stream>>>(bufB, W2, b2, bufA, N);
    k_stats_fin<<<256, 256, 0, stream>>>(bufA, sum2, sq2, g2, mu2, coef2, cnt2, N);
    k_bnmean_fin<<<256, 256, 0, stream>>>(bufA, mu2, coef2, be2, hsum, Wc, bc, out, cnt3, N);
}